// Round 1
// baseline (2380.032 us; speedup 1.0000x reference)
//
#include <hip/hip_runtime.h>

using bf16x8 = __attribute__((ext_vector_type(8))) short;
using f32x4  = __attribute__((ext_vector_type(4))) float;

__device__ inline float bf2f(unsigned short h){
  union { unsigned int u; float f; } v; v.u = ((unsigned int)h) << 16; return v.f;
}
__device__ inline unsigned short f2b(float x){
  union { float f; unsigned int u; } v; v.f = x;
  unsigned int r = (v.u + 0x7FFFu + ((v.u >> 16) & 1u)) >> 16;
  return (unsigned short)r;
}

// ---------------------------------------------------------------------------
// fp32 -> bf16 bulk convert (n multiple of 4)
__global__ void conv_k(const float* __restrict__ s, unsigned short* __restrict__ d, int n){
  int i = (blockIdx.x * 256 + threadIdx.x) * 4;
  if (i >= n) return;
  float4 v = *(const float4*)(s + i);
  unsigned int p0 = (unsigned int)f2b(v.x) | ((unsigned int)f2b(v.y) << 16);
  unsigned int p1 = (unsigned int)f2b(v.z) | ((unsigned int)f2b(v.w) << 16);
  *(uint2*)(d + i) = make_uint2(p0, p1);
}

// embedding gather (pad_idx=2 -> 0), rows m = t*64+b, bf16 out
__global__ void embed_k(const int* __restrict__ tgt, const float* __restrict__ emb,
                        unsigned short* __restrict__ out, int n){
  int idx = blockIdx.x * 256 + threadIdx.x;
  if (idx >= n) return;
  int d = idx & 511, m = idx >> 9, t = m >> 6, b = m & 63;
  int tok = tgt[b * 32 + t];
  float v = (tok == 2) ? 0.f : emb[(long)tok * 512 + d];
  out[idx] = f2b(v);
}

// ---------------------------------------------------------------------------
// Generic bf16 MFMA GEMM: C[m][n] = sum_k A[m][k]*B[n][k] (+bias[n])
// BM=64, BN=256, block 256 threads (4 waves, each wave 64x64 via 4x4 frags).
// M % 64 == 0, N % 256 == 0, K % 32 == 0 for all instances (true here).
// EPI: 0 plain fp32, 1 tanh + dual fp32/bf16 write, 2 logits scatter (b,t,v).
// n_split>0: dual-source (blocks with n0>=n_split use A2/B2, B row = n0-n_split).
#define EPI_PLAIN 0
#define EPI_TANH  1
#define EPI_OUT   2

template<int EPI, bool AF32>
__global__ __launch_bounds__(256)
void gemm_bt(const void* __restrict__ Av, int lda,
             const unsigned short* __restrict__ Bp, int ldb,
             const float* __restrict__ bias,
             float* __restrict__ Cf, unsigned short* __restrict__ Cb, int ldc,
             int K,
             int n_split, const void* __restrict__ A2v,
             const unsigned short* __restrict__ B2p, int lda2, int ldb2)
{
  // pad LDS rows to 40 ushorts (bank stride 20 -> <=2-way conflicts, free)
  __shared__ __align__(16) unsigned short As[64][40];
  __shared__ __align__(16) unsigned short Bs[256][40];

  int m0 = blockIdx.x * 64;
  int n0 = blockIdx.y * 256;
  const void* Ap = Av; const unsigned short* Bq = Bp;
  int la = lda, lb = ldb, nB = n0;
  if (n_split > 0 && n0 >= n_split){ Ap = A2v; Bq = B2p; la = lda2; lb = ldb2; nB = n0 - n_split; }

  int tid  = threadIdx.x;
  int wave = tid >> 6, lane = tid & 63, quad = lane >> 4, lrow = lane & 15;

  f32x4 acc[4][4];
#pragma unroll
  for (int i = 0; i < 4; ++i)
#pragma unroll
    for (int j = 0; j < 4; ++j)
#pragma unroll
      for (int r = 0; r < 4; ++r) acc[i][j][r] = 0.f;

  int ar = tid >> 2, ac = (tid & 3) * 8;   // A staging: 8 elems/thread

  for (int k0 = 0; k0 < K; k0 += 32){
    // stage A tile 64x32
    if (AF32){
      const float* A32 = (const float*)Ap;
      const float4* src = (const float4*)(A32 + (long)(m0 + ar) * la + k0 + ac);
      float4 x0 = src[0], x1 = src[1];
      unsigned int p0 = (unsigned int)f2b(x0.x) | ((unsigned int)f2b(x0.y) << 16);
      unsigned int p1 = (unsigned int)f2b(x0.z) | ((unsigned int)f2b(x0.w) << 16);
      unsigned int p2 = (unsigned int)f2b(x1.x) | ((unsigned int)f2b(x1.y) << 16);
      unsigned int p3 = (unsigned int)f2b(x1.z) | ((unsigned int)f2b(x1.w) << 16);
      *(uint4*)&As[ar][ac] = make_uint4(p0, p1, p2, p3);
    } else {
      const unsigned short* A16 = (const unsigned short*)Ap;
      *(uint4*)&As[ar][ac] = *(const uint4*)(A16 + (long)(m0 + ar) * la + k0 + ac);
    }
    // stage B tile 256x32 (4 chunks of 8 per thread)
#pragma unroll
    for (int c = 0; c < 4; ++c){
      int id = tid + c * 256; int br = id >> 2, bc = (id & 3) * 8;
      *(uint4*)&Bs[br][bc] = *(const uint4*)(Bq + (long)(nB + br) * lb + k0 + bc);
    }
    __syncthreads();

    bf16x8 af[4], bfr[4];
#pragma unroll
    for (int mf = 0; mf < 4; ++mf) af[mf]  = *(const bf16x8*)&As[mf * 16 + lrow][quad * 8];
#pragma unroll
    for (int nf = 0; nf < 4; ++nf) bfr[nf] = *(const bf16x8*)&Bs[wave * 64 + nf * 16 + lrow][quad * 8];
#pragma unroll
    for (int mf = 0; mf < 4; ++mf)
#pragma unroll
      for (int nf = 0; nf < 4; ++nf)
        acc[mf][nf] = __builtin_amdgcn_mfma_f32_16x16x32_bf16(af[mf], bfr[nf], acc[mf][nf], 0, 0, 0);
    __syncthreads();
  }

#pragma unroll
  for (int mf = 0; mf < 4; ++mf){
#pragma unroll
    for (int nf = 0; nf < 4; ++nf){
#pragma unroll
      for (int r = 0; r < 4; ++r){
        int m = m0 + mf * 16 + quad * 4 + r;
        int n = n0 + wave * 64 + nf * 16 + lrow;
        float v = acc[mf][nf][r];
        if (bias) v += bias[n];
        if (EPI == EPI_TANH){
          v = tanhf(v);
          Cf[(long)m * ldc + n] = v;
          Cb[(long)m * ldc + n] = f2b(v);
        } else if (EPI == EPI_OUT){
          // m = t*64+b -> out[b][t][n]
          Cf[(long)(m & 63) * (31 * 32000) + (long)(m >> 6) * 32000 + n] = v;
        } else {
          Cf[(long)m * ldc + n] = v;
        }
      }
    }
  }
}

// ---------------------------------------------------------------------------
// Per-step fused kernel: (optional) GRU gates for step t-1 producing h_t,
// then Bahdanau attention with h_t producing context (bf16). 1 block / batch.
__global__ __launch_bounds__(512)
void attn_step(const float* __restrict__ enc_proj,
               const float* __restrict__ enc_out,
               const float* __restrict__ W_score,
               const float* __restrict__ b_dec,
               const float* __restrict__ b_hh,
               const float* __restrict__ gi_emb,
               const float* __restrict__ giq,
               float* __restrict__ h_all,
               unsigned short* __restrict__ h_b16,
               const unsigned short* __restrict__ Wdec,
               unsigned short* __restrict__ ctx_b16,
               int t, int do_gates, int do_attn)
{
  int b = blockIdx.x, tid = threadIdx.x;
  __shared__ float sh_h[512];
  __shared__ float sdp[256];
  __shared__ float sbuf[512];
  __shared__ float sw[256];
  __shared__ float sred[512];
  __shared__ float swsc[256];

  float hv;
  if (do_gates){
    int j = tid;
    long ge = ((long)(t - 1) * 64 + b) * 1536;
    long gq = (long)b * 3072;
    float gir = gi_emb[ge + j]        + giq[gq + j];
    float giz = gi_emb[ge + 512 + j]  + giq[gq + 512 + j];
    float gin = gi_emb[ge + 1024 + j] + giq[gq + 1024 + j];
    float ghr = giq[gq + 1536 + j]        + b_hh[j];
    float ghz = giq[gq + 1536 + 512 + j]  + b_hh[512 + j];
    float ghn = giq[gq + 1536 + 1024 + j] + b_hh[1024 + j];
    float rr = 1.f / (1.f + __expf(-(gir + ghr)));
    float zz = 1.f / (1.f + __expf(-(giz + ghz)));
    float nn = tanhf(gin + rr * ghn);
    float hp = h_all[((long)(t - 1) * 64 + b) * 512 + j];
    hv = (1.f - zz) * nn + zz * hp;
    h_all[((long)t * 64 + b) * 512 + j] = hv;
    h_b16[((long)t * 64 + b) * 512 + j] = f2b(hv);
  } else {
    hv = h_all[((long)t * 64 + b) * 512 + tid];
  }
  sh_h[tid] = hv;
  if (tid < 256) swsc[tid] = W_score[tid];
  __syncthreads();
  if (!do_attn) return;

  // dec_proj[a] = h . Wdec[a,:] + b_dec[a], split K over 2 half-threads
  {
    int a = tid & 255, half = tid >> 8;
    const uint4* wp = (const uint4*)(Wdec + a * 512 + half * 256);
    const float* hp = &sh_h[half * 256];
    float acc = 0.f;
#pragma unroll 8
    for (int c = 0; c < 32; ++c){
      uint4 wv = wp[c];
      acc += hp[c*8+0] * bf2f((unsigned short)(wv.x & 0xffff));
      acc += hp[c*8+1] * bf2f((unsigned short)(wv.x >> 16));
      acc += hp[c*8+2] * bf2f((unsigned short)(wv.y & 0xffff));
      acc += hp[c*8+3] * bf2f((unsigned short)(wv.y >> 16));
      acc += hp[c*8+4] * bf2f((unsigned short)(wv.z & 0xffff));
      acc += hp[c*8+5] * bf2f((unsigned short)(wv.z >> 16));
      acc += hp[c*8+6] * bf2f((unsigned short)(wv.w & 0xffff));
      acc += hp[c*8+7] * bf2f((unsigned short)(wv.w >> 16));
    }
    sbuf[tid] = acc;
    __syncthreads();
    if (tid < 256) sdp[tid] = sbuf[tid] + sbuf[tid + 256] + b_dec[tid];
    __syncthreads();
  }

  // scores[s] = sum_a wsc[a]*tanh(enc_proj[b,s,a]+dec_proj[a]); split a over 2
  {
    int s = tid & 255, half = tid >> 8;
    float acc = 0.f;
    if (s < 196){
      const float* ep = enc_proj + ((long)b * 196 + s) * 256 + half * 128;
      const float* dp = &sdp[half * 128];
      const float* wv = &swsc[half * 128];
#pragma unroll 4
      for (int a = 0; a < 128; ++a){
        float x = ep[a] + dp[a];
        float e = __expf(2.f * x);
        acc += wv[a] * (1.f - 2.f / (e + 1.f));
      }
    }
    sbuf[tid] = acc;
    __syncthreads();
    float sc = (tid < 196) ? (sbuf[tid] + sbuf[tid + 256]) : -1e30f;
    sred[tid] = sc; __syncthreads();
    for (int off = 256; off > 0; off >>= 1){
      if (tid < off) sred[tid] = fmaxf(sred[tid], sred[tid + off]);
      __syncthreads();
    }
    float mx = sred[0]; __syncthreads();
    float e = (tid < 196) ? __expf(sc - mx) : 0.f;
    sred[tid] = e; __syncthreads();
    for (int off = 256; off > 0; off >>= 1){
      if (tid < off) sred[tid] += sred[tid + off];
      __syncthreads();
    }
    float inv = 1.f / sred[0];
    if (tid < 196) sw[tid] = e * inv;
    __syncthreads();
  }

  // context[e] = sum_s w[s]*enc_out[b,s,e]; coalesced over e
  {
    const float* ep = enc_out + (long)b * 196 * 512 + tid;
    float acc = 0.f;
#pragma unroll 4
    for (int s = 0; s < 196; ++s) acc += sw[s] * ep[(long)s * 512];
    ctx_b16[b * 512 + tid] = f2b(acc);
  }
}

// ---------------------------------------------------------------------------
extern "C" void kernel_launch(void* const* d_in, const int* in_sizes, int n_in,
                              void* d_out, int out_size, void* d_ws, size_t ws_size,
                              hipStream_t stream)
{
  (void)in_sizes; (void)n_in; (void)out_size; (void)ws_size;
  const float* encoder_out = (const float*)d_in[0];
  const float* pooled      = (const float*)d_in[1];
  const int*   targets     = (const int*)d_in[2];
  const float* embedding   = (const float*)d_in[3];
  const float* W_enc  = (const float*)d_in[4];
  const float* b_enc  = (const float*)d_in[5];
  const float* W_dec  = (const float*)d_in[6];
  const float* b_dec  = (const float*)d_in[7];
  const float* W_score= (const float*)d_in[8];
  const float* W_ih   = (const float*)d_in[10];
  const float* W_hh   = (const float*)d_in[11];
  const float* b_ih   = (const float*)d_in[12];
  const float* b_hh   = (const float*)d_in[13];
  const float* W_out  = (const float*)d_in[14];
  const float* b_out  = (const float*)d_in[15];
  const float* W_init = (const float*)d_in[16];
  const float* b_init = (const float*)d_in[17];
  float* out = (float*)d_out;

  char* w = (char*)d_ws;
  float* enc_proj         = (float*)w;          w += 12845056;  // 64*196*256 f32
  float* gi_emb           = (float*)w;          w += 12189696;  // 31*64*1536 f32
  float* h_all            = (float*)w;          w += 4194304;   // 32*64*512 f32
  unsigned short* h_b16   = (unsigned short*)w; w += 2097152;   // 32*64*512 bf16
  float* giq              = (float*)w;          w += 786432;    // 64*3072 f32
  unsigned short* ctx_b16 = (unsigned short*)w; w += 65536;     // 64*512 bf16
  unsigned short* emb_b16 = (unsigned short*)w; w += 2031616;   // 1984*512 bf16
  unsigned short* Wout_b  = (unsigned short*)w; w += 32768000;
  unsigned short* Wih_b   = (unsigned short*)w; w += 3145728;
  unsigned short* Whh_b   = (unsigned short*)w; w += 1572864;
  unsigned short* Wdec_b  = (unsigned short*)w; w += 262144;
  unsigned short* Winit_b = (unsigned short*)w; w += 524288;
  unsigned short* Wenc_b  = (unsigned short*)w; w += 262144;

  auto conv = [&](const float* s, unsigned short* d, int n){
    conv_k<<<dim3((n / 4 + 255) / 256), dim3(256), 0, stream>>>(s, d, n);
  };
  conv(W_out,  Wout_b,  32000 * 512);
  conv(W_ih,   Wih_b,   1536 * 1024);
  conv(W_hh,   Whh_b,   1536 * 512);
  conv(W_dec,  Wdec_b,  256 * 512);
  conv(W_init, Winit_b, 512 * 512);
  conv(W_enc,  Wenc_b,  256 * 512);
  embed_k<<<dim3((1984 * 512) / 256), dim3(256), 0, stream>>>(targets, embedding, emb_b16, 1984 * 512);

  // h0 = tanh(pooled @ W_init^T + b_init)
  gemm_bt<EPI_TANH, true><<<dim3(1, 2), 256, 0, stream>>>(
      pooled, 512, Winit_b, 512, b_init, h_all, h_b16, 512, 512, 0, nullptr, nullptr, 0, 0);
  // enc_proj = encoder_out @ W_enc^T + b_enc  (M=12544)
  gemm_bt<EPI_PLAIN, true><<<dim3(196, 1), 256, 0, stream>>>(
      encoder_out, 512, Wenc_b, 512, b_enc, enc_proj, nullptr, 256, 512, 0, nullptr, nullptr, 0, 0);
  // gi_emb = embedded @ W_ih[:, :512]^T + b_ih  (M=1984)
  gemm_bt<EPI_PLAIN, false><<<dim3(31, 6), 256, 0, stream>>>(
      emb_b16, 512, Wih_b, 1024, b_ih, gi_emb, nullptr, 1536, 512, 0, nullptr, nullptr, 0, 0);

  for (int t = 0; t < 31; ++t){
    attn_step<<<dim3(64), dim3(512), 0, stream>>>(
        enc_proj, encoder_out, W_score, b_dec, b_hh, gi_emb, giq,
        h_all, h_b16, Wdec_b, ctx_b16, t, (t > 0) ? 1 : 0, 1);
    // giq[:, 0:1536] = W_ih[:,512:] . ctx ; giq[:, 1536:3072] = W_hh . h_t
    gemm_bt<EPI_PLAIN, false><<<dim3(1, 12), 256, 0, stream>>>(
        ctx_b16, 512, Wih_b + 512, 1024, nullptr, giq, nullptr, 3072, 512,
        1536, h_b16 + (long)t * 64 * 512, Whh_b, 512, 512);
  }
  // final gates: h_31
  attn_step<<<dim3(64), dim3(512), 0, stream>>>(
      enc_proj, encoder_out, W_score, b_dec, b_hh, gi_emb, giq,
      h_all, h_b16, Wdec_b, ctx_b16, 31, 1, 0);

  // logits: (1984 x 32000 x 512), A = h_1..h_31, scatter to (b,t,v)
  gemm_bt<EPI_OUT, false><<<dim3(31, 125), 256, 0, stream>>>(
      h_b16 + 64 * 512, 512, Wout_b, 512, b_out, out, nullptr, 0, 512,
      0, nullptr, nullptr, 0, 0);
}